// Round 15
// baseline (883.162 us; speedup 1.0000x reference)
//
#include <hip/hip_runtime.h>
#include <hip/hip_cooperative_groups.h>
#include <cmath>

namespace cg = cooperative_groups;

#define N_NODES 4096
#define FDIM    256
#define CDIM    40
#define NEDGE   131072
#define CAP     256                  // ELL row capacity (row nnz ~Poisson(64))
#define HBITS   20
#define HSIZE   (1 << HBITS)         // 1M hash slots, load <= 0.125
#define TWO_PI_F 6.28318530717958647692f
#define GRID    512                  // cooperative grid (2 blocks/CU guaranteed)
#define NWT     (256 * 768)

typedef __bf16 bf16;
typedef __bf16 bf16x2 __attribute__((ext_vector_type(2)));
typedef __bf16 bf16x4 __attribute__((ext_vector_type(4)));
typedef __bf16 bf16x8 __attribute__((ext_vector_type(8)));
typedef float  f32x4  __attribute__((ext_vector_type(4)));

static constexpr size_t NF = (size_t)N_NODES * FDIM;      // 1,048,576
static constexpr int ZWORDS = 2 * HSIZE + 3 * N_NODES;    // hkey+hval+cnt+rowsum+colsum

struct __align__(16) Entry { float lr, li; int col, pad; };

struct Params {
    const int* edges; const float* ew; const float* q;
    const float* real; const float* imag;
    const float* W1; const float* b1; const float* W2; const float* b2;
    const float* Wc; const float* bc;
    int* hkey; float* hval; int* cnt; float* rowsum; float* colsum;
    Entry* ent;
    bf16 *Xr16, *Xi16, *XC;
    bf16 *Z1r, *Z1i, *Z1C, *Z2r, *Z2i;
    bf16 *Y1rb, *Y1ib, *Y1C, *Y2rb, *Y2ib;
    bf16 *W1t, *W2t, *Wcb;
    float* out;
};

// async global->LDS, 16B per lane, dest = ldsBase + lane*16
__device__ __forceinline__ void gld_lds16(const bf16* g, bf16* s) {
    __builtin_amdgcn_global_load_lds(
        (const __attribute__((address_space(1))) void*)g,
        (__attribute__((address_space(3))) void*)s,
        16, 0, 0);
}

__device__ __forceinline__ unsigned cell_hash(unsigned cell) {
    return (cell * 2654435761u) >> (32 - HBITS);
}

// ---------------------------------------------------------------------------
// Stage bodies (shared between mega kernel and fallback wrappers)
// ---------------------------------------------------------------------------
__device__ void init_stage(const Params& p, int gtid, int stride) {
    int* zw = (int*)p.hkey;   // hkey,hval,cnt,rowsum,colsum contiguous
    for (int w0 = gtid; w0 < ZWORDS; w0 += stride) zw[w0] = 0;

    for (int idx = gtid; idx < (int)NF; idx += stride) {
        float vr = p.real[idx], vi = p.imag[idx];
        p.Xr16[idx] = (bf16)vr; p.Xi16[idx] = (bf16)vi;
        bf16x2 pp; pp[0] = (bf16)vr; pp[1] = (bf16)vi;
        ((bf16x2*)p.XC)[idx] = pp;
    }
    for (int idx = gtid; idx < 2 * NWT + 48 * 512; idx += stride) {
        if (idx < 2 * NWT) {
            const float* W = (idx < NWT) ? p.W1 : p.W2;
            bf16* Wt = (idx < NWT) ? p.W1t : p.W2t;
            int id = (idx < NWT) ? idx : idx - NWT;
            int nout = id / 768, kk = id - nout * 768;
            int o = kk >> 8, k = kk & 255;
            Wt[id] = (bf16)W[((size_t)o * 256 + k) * 256 + nout];
        } else {
            int id = idx - 2 * NWT;
            int row = id >> 9, k = id & 511;
            p.Wcb[id] = (row < CDIM) ? (bf16)p.Wc[row * 512 + k] : (bf16)0.f;
        }
    }
}

__device__ void hash_stage(const Params& p, int gtid, int stride) {
    for (int e = gtid; e < NEDGE; e += stride) {
        int r = p.edges[e], c = p.edges[NEDGE + e];
        float wv = p.ew[e];
        atomicAdd(p.rowsum + r, wv);
        atomicAdd(p.colsum + c, wv);
        unsigned cell = (unsigned)r * N_NODES + c;
        unsigned h = cell_hash(cell);
        for (;;) {
            int old = atomicCAS(p.hkey + h, 0, (int)(cell + 1));
            if (old == 0 || old == (int)(cell + 1)) { atomicAdd(p.hval + h, wv); break; }
            h = (h + 1) & (HSIZE - 1);
        }
    }
}

__device__ void ell_stage(const Params& p, int gtid, int stride) {
    for (int h = gtid; h < HSIZE; h += stride) {
        int k = p.hkey[h];
        if (k == 0) continue;
        unsigned cell = (unsigned)(k - 1);
        int i = cell >> 12, j = cell & 4095;
        float a = p.hval[h];
        float b = 0.f;
        bool mirror = false;
        if (i == j) { b = a; mirror = true; }
        else {
            unsigned mcell = (unsigned)j * N_NODES + i;
            unsigned hh = cell_hash(mcell);
            for (;;) {
                int kk = p.hkey[hh];
                if (kk == (int)(mcell + 1)) { b = p.hval[hh]; mirror = true; break; }
                if (kk == 0) break;
                hh = (hh + 1) & (HSIZE - 1);
            }
        }
        float di = 0.5f * (p.rowsum[i] + p.colsum[i]); if (di == 0.f) di = 1.f;
        float dj = 0.5f * (p.rowsum[j] + p.colsum[j]); if (dj == 0.f) dj = 1.f;
        float an = 0.5f * (a + b) / sqrtf(di * dj);
        float s, c;
        sincosf(TWO_PI_F * p.q[0] * (a - b), &s, &c);
        int pos = atomicAdd(p.cnt + i, 1);
        if (pos < CAP) {
            Entry en; en.lr = -an * c; en.li = an * s; en.col = j; en.pad = 0;
            p.ent[(size_t)i * CAP + pos] = en;
        }
        if (!mirror) {
            int pos2 = atomicAdd(p.cnt + j, 1);
            if (pos2 < CAP) {
                Entry en; en.lr = -an * c; en.li = -an * s; en.col = i; en.pad = 0;
                p.ent[(size_t)j * CAP + pos2] = en;
            }
        }
    }
}

// spmm stage (R8/R13-proven math): 8 rows per block (grid 512)
__device__ void spmm_stage(const int* __restrict__ cnt, const Entry* __restrict__ ent,
                           const bf16* __restrict__ XC, const bf16* __restrict__ C0C,
                           float alpha, float beta,
                           bf16* __restrict__ Zr, bf16* __restrict__ Zi,
                           bf16* __restrict__ ZC, char* smem, int bid)
{
    f32x4* redR = (f32x4*)smem;          // [3][64]
    f32x4* redI = redR + 192;            // [3][64]
    const int wave = threadIdx.x >> 6, lane = threadIdx.x & 63;

    for (int rr = 0; rr < 8; ++rr) {
        const int row = bid * 8 + rr;
        int n1 = cnt[row]; if (n1 > CAP) n1 = CAP;
        const Entry* erow = ent + (size_t)row * CAP;

        float ar[4] = {}, ai[4] = {};
        int e = wave;
        for (; e + 12 < n1; e += 16) {
            Entry e0 = erow[e];
            Entry e1 = erow[e + 4];
            Entry e2 = erow[e + 8];
            Entry e3 = erow[e + 12];
            bf16x8 x0 = *(const bf16x8*)&XC[(size_t)(e0.col & 4095) * 512 + lane * 8];
            bf16x8 x1 = *(const bf16x8*)&XC[(size_t)(e1.col & 4095) * 512 + lane * 8];
            bf16x8 x2 = *(const bf16x8*)&XC[(size_t)(e2.col & 4095) * 512 + lane * 8];
            bf16x8 x3 = *(const bf16x8*)&XC[(size_t)(e3.col & 4095) * 512 + lane * 8];
            #pragma unroll
            for (int c = 0; c < 4; ++c) {
                float xr, xi;
                xr = (float)x0[2 * c]; xi = (float)x0[2 * c + 1];
                ar[c] += e0.lr * xr - e0.li * xi;  ai[c] += e0.lr * xi + e0.li * xr;
                xr = (float)x1[2 * c]; xi = (float)x1[2 * c + 1];
                ar[c] += e1.lr * xr - e1.li * xi;  ai[c] += e1.lr * xi + e1.li * xr;
                xr = (float)x2[2 * c]; xi = (float)x2[2 * c + 1];
                ar[c] += e2.lr * xr - e2.li * xi;  ai[c] += e2.lr * xi + e2.li * xr;
                xr = (float)x3[2 * c]; xi = (float)x3[2 * c + 1];
                ar[c] += e3.lr * xr - e3.li * xi;  ai[c] += e3.lr * xi + e3.li * xr;
            }
        }
        for (; e < n1; e += 4) {
            Entry e0 = erow[e];
            bf16x8 x0 = *(const bf16x8*)&XC[(size_t)(e0.col & 4095) * 512 + lane * 8];
            #pragma unroll
            for (int c = 0; c < 4; ++c) {
                float xr0 = (float)x0[2 * c], xi0 = (float)x0[2 * c + 1];
                ar[c] += e0.lr * xr0 - e0.li * xi0;
                ai[c] += e0.lr * xi0 + e0.li * xr0;
            }
        }

        if (wave != 0) {
            f32x4 r, i;
            #pragma unroll
            for (int c = 0; c < 4; ++c) { r[c] = ar[c]; i[c] = ai[c]; }
            redR[(wave - 1) * 64 + lane] = r;
            redI[(wave - 1) * 64 + lane] = i;
        }
        __syncthreads();
        if (wave == 0) {
            #pragma unroll
            for (int w = 0; w < 3; ++w) {
                f32x4 r = redR[w * 64 + lane], i = redI[w * 64 + lane];
                #pragma unroll
                for (int c = 0; c < 4; ++c) { ar[c] += r[c]; ai[c] += i[c]; }
            }
            float vr[4], vi[4];
            if (beta != 0.f) {
                bf16x8 c0 = *(const bf16x8*)&C0C[(size_t)row * 512 + lane * 8];
                #pragma unroll
                for (int c = 0; c < 4; ++c) {
                    vr[c] = alpha * ar[c] + beta * (float)c0[2 * c];
                    vi[c] = alpha * ai[c] + beta * (float)c0[2 * c + 1];
                }
            } else {
                #pragma unroll
                for (int c = 0; c < 4; ++c) { vr[c] = alpha * ar[c]; vi[c] = alpha * ai[c]; }
            }
            size_t base = (size_t)row * FDIM + lane * 4;
            bf16x4 pr, pi;
            #pragma unroll
            for (int c = 0; c < 4; ++c) { pr[c] = (bf16)vr[c]; pi[c] = (bf16)vi[c]; }
            *(bf16x4*)&Zr[base] = pr;
            *(bf16x4*)&Zi[base] = pi;
            if (ZC) {
                bf16x8 o;
                #pragma unroll
                for (int c = 0; c < 4; ++c) { o[2 * c] = pr[c]; o[2 * c + 1] = pi[c]; }
                *(bf16x8*)&ZC[(size_t)row * 512 + lane * 8] = o;
            }
        }
        __syncthreads();   // protect LDS reuse for next row
    }
}

// wapply stage (R3/R7/R9-proven math; caller guarantees bid < 256)
__device__ void wapply_stage(const bf16* __restrict__ Z0r, const bf16* __restrict__ Z0i,
                             const bf16* __restrict__ Z1r, const bf16* __restrict__ Z1i,
                             const bf16* __restrict__ Z2r, const bf16* __restrict__ Z2i,
                             const bf16* __restrict__ Wt, const float* __restrict__ bias,
                             bf16* __restrict__ Or, bf16* __restrict__ Oi,
                             bf16* __restrict__ OC, char* smem, int bid)
{
    bf16* sZr = (bf16*)smem;
    bf16* sZi = (bf16*)(smem + 4096);
    bf16* sW  = (bf16*)(smem + 8192);

    const int tid  = threadIdx.x;
    const int wave = tid >> 6;
    const int lane = tid & 63;
    const int rowBase = (bid >> 2) * 64;
    const int colBase = (bid & 3) * 64;

    const int srow = lane >> 2;
    const int skc  = (lane & 3) * 8;

    f32x4 accSr[2][2] = {}, accSi[2][2] = {};
    const int wm = wave & 1, wn = wave >> 1;
    const int fr = lane & 15;
    const int fk = (lane >> 4) * 8;

    for (int kb = 0; kb < 3 * FDIM; kb += 32) {
        int order = kb >> 8;
        int kloc  = kb & 255;
        if (wave == 0 || wave == 1) {
            const bf16* z;
            if (wave == 0) z = (order == 0) ? Z0r : (order == 1) ? Z1r : Z2r;
            else           z = (order == 0) ? Z0i : (order == 1) ? Z1i : Z2i;
            bf16* s = (wave == 0) ? sZr : sZi;
            const bf16* g = z + (size_t)(rowBase + srow) * FDIM + kloc + skc;
            #pragma unroll
            for (int t = 0; t < 4; ++t)
                gld_lds16(g + (size_t)t * 16 * FDIM, s + t * 512);
        } else if (wave == 2) {
            const bf16* g = Wt + (size_t)(colBase + srow) * 768 + kb + skc;
            #pragma unroll
            for (int t = 0; t < 4; ++t)
                gld_lds16(g + (size_t)t * 16 * 768, sW + t * 512);
        }
        __syncthreads();

        bf16x8 zr[2], zi[2], wv[2];
        #pragma unroll
        for (int m = 0; m < 2; ++m) {
            int r = wm * 32 + m * 16 + fr;
            zr[m] = *(const bf16x8*)&sZr[r * 32 + fk];
            zi[m] = *(const bf16x8*)&sZi[r * 32 + fk];
        }
        #pragma unroll
        for (int n = 0; n < 2; ++n) {
            int c = wn * 32 + n * 16 + fr;
            wv[n] = *(const bf16x8*)&sW[c * 32 + fk];
        }
        #pragma unroll
        for (int m = 0; m < 2; ++m)
            #pragma unroll
            for (int n = 0; n < 2; ++n) {
                accSr[m][n] = __builtin_amdgcn_mfma_f32_16x16x32_bf16(zr[m], wv[n], accSr[m][n], 0, 0, 0);
                accSi[m][n] = __builtin_amdgcn_mfma_f32_16x16x32_bf16(zi[m], wv[n], accSi[m][n], 0, 0, 0);
            }
        __syncthreads();
    }

    #pragma unroll
    for (int m = 0; m < 2; ++m)
        #pragma unroll
        for (int n = 0; n < 2; ++n) {
            int row0 = rowBase + wm * 32 + m * 16 + (lane >> 4) * 4;
            int col  = colBase + wn * 32 + n * 16 + (lane & 15);
            float bv = bias[col];
            #pragma unroll
            for (int r = 0; r < 4; ++r) {
                float vr = bv - accSi[m][n][r];
                float vi = bv + accSr[m][n][r];
                size_t idx = (size_t)(row0 + r) * FDIM + col;
                Or[idx] = (bf16)vr; Oi[idx] = (bf16)vi;
                if (OC) {
                    bf16x2 pp; pp[0] = (bf16)vr; pp[1] = (bf16)vi;
                    ((bf16x2*)OC)[idx] = pp;
                }
            }
        }
}

// head stage (R11-proven math; caller guarantees bid < 64)
__device__ void head_stage(const bf16* __restrict__ Yrb, const bf16* __restrict__ Yib,
                           const bf16* __restrict__ Wcb, const float* __restrict__ bc,
                           float* __restrict__ out, char* smem, int bid)
{
    bf16*  sY = (bf16*)smem;                       // [64][72]
    bf16*  sW = (bf16*)(smem + 9216);              // [48][72]
    float* sS = (float*)(smem + 9216 + 6912);      // [64][52]

    const int tid  = threadIdx.x;
    const int wave = tid >> 6;
    const int lane = tid & 63;
    const int r0 = bid * 64;

    f32x4 acc[3] = {};

    for (int kb = 0; kb < 512; kb += 64) {
        const bf16* src = (kb < 256) ? Yrb : Yib;
        const int koff = kb & 255;
        #pragma unroll
        for (int e = 0; e < 2; ++e) {
            int idx = tid + e * 256;
            int rr = idx >> 3, kk = (idx & 7) * 8;
            *(bf16x8*)&sY[rr * 72 + kk] =
                *(const bf16x8*)&src[(size_t)(r0 + rr) * FDIM + koff + kk];
        }
        #pragma unroll
        for (int e = 0; e < 2; ++e) {
            int idx = tid + e * 256;
            if (idx < 384) {
                int rr = idx >> 3, kk = (idx & 7) * 8;
                *(bf16x8*)&sW[rr * 72 + kk] =
                    *(const bf16x8*)&Wcb[(size_t)rr * 512 + kb + kk];
            }
        }
        __syncthreads();
        #pragma unroll
        for (int ks = 0; ks < 2; ++ks) {
            bf16x8 a = *(const bf16x8*)&sY[(wave * 16 + (lane & 15)) * 72 + ks * 32 + (lane >> 4) * 8];
            #pragma unroll
            for (int n = 0; n < 3; ++n) {
                bf16x8 b = *(const bf16x8*)&sW[(n * 16 + (lane & 15)) * 72 + ks * 32 + (lane >> 4) * 8];
                acc[n] = __builtin_amdgcn_mfma_f32_16x16x32_bf16(a, b, acc[n], 0, 0, 0);
            }
        }
        __syncthreads();
    }

    #pragma unroll
    for (int n = 0; n < 3; ++n) {
        int col = n * 16 + (lane & 15);
        int rloc = wave * 16 + (lane >> 4) * 4;
        #pragma unroll
        for (int r = 0; r < 4; ++r)
            sS[(rloc + r) * 52 + col] = acc[n][r];
    }
    __syncthreads();

    if (tid < 64) {
        float mx = -INFINITY;
        #pragma unroll 8
        for (int c = 0; c < CDIM; ++c) {
            float lv = sS[tid * 52 + c] + bc[c];
            sS[tid * 52 + c] = lv;
            mx = fmaxf(mx, lv);
        }
        float se = 0.f;
        #pragma unroll 8
        for (int c = 0; c < CDIM; ++c) se += expf(sS[tid * 52 + c] - mx);
        float lse = mx + logf(se);
        #pragma unroll 8
        for (int c = 0; c < CDIM; ++c)
            out[(size_t)(r0 + tid) * CDIM + c] = sS[tid * 52 + c] - lse;
    }
    __syncthreads();
}

// ---------------------------------------------------------------------------
// Mega cooperative kernel: grid 512 x 256, launch_bounds(256,2) -> 2 blocks/CU
// guaranteed co-residency with 2.7x LDS headroom (29.4KB/block).
// ---------------------------------------------------------------------------
__global__ __launch_bounds__(256, 2) void mega(Params p) {
    cg::grid_group grid = cg::this_grid();
    __shared__ __align__(16) char smem[29440];

    const int bid  = blockIdx.x;
    const int tid  = threadIdx.x;
    const int gtid = bid * 256 + tid;
    const int stride = gridDim.x * 256;

    init_stage(p, gtid, stride);
    grid.sync();
    hash_stage(p, gtid, stride);
    grid.sync();
    ell_stage(p, gtid, stride);
    grid.sync();

    // Layer 1
    spmm_stage(p.cnt, p.ent, p.XC, nullptr, 1.f, 0.f, p.Z1r, p.Z1i, p.Z1C, smem, bid);
    grid.sync();
    spmm_stage(p.cnt, p.ent, p.Z1C, p.XC, 2.f, -1.f, p.Z2r, p.Z2i, nullptr, smem, bid);
    grid.sync();
    if (bid < 256)
        wapply_stage(p.Xr16, p.Xi16, p.Z1r, p.Z1i, p.Z2r, p.Z2i,
                     p.W1t, p.b1, p.Y1rb, p.Y1ib, p.Y1C, smem, bid);
    grid.sync();

    // Layer 2
    spmm_stage(p.cnt, p.ent, p.Y1C, nullptr, 1.f, 0.f, p.Z1r, p.Z1i, p.Z1C, smem, bid);
    grid.sync();
    spmm_stage(p.cnt, p.ent, p.Z1C, p.Y1C, 2.f, -1.f, p.Z2r, p.Z2i, nullptr, smem, bid);
    grid.sync();
    if (bid < 256)
        wapply_stage(p.Y1rb, p.Y1ib, p.Z1r, p.Z1i, p.Z2r, p.Z2i,
                     p.W2t, p.b2, p.Y2rb, p.Y2ib, nullptr, smem, bid);
    grid.sync();

    // Head
    if (bid < 64)
        head_stage(p.Y2rb, p.Y2ib, p.Wcb, p.bc, p.out, smem, bid);
}

// ---------------------------------------------------------------------------
// Fallback wrappers (multi-kernel path, same device bodies)
// ---------------------------------------------------------------------------
__global__ __launch_bounds__(256) void k_init(Params p) {
    init_stage(p, blockIdx.x * 256 + threadIdx.x, gridDim.x * 256);
}
__global__ __launch_bounds__(256) void k_hash(Params p) {
    hash_stage(p, blockIdx.x * 256 + threadIdx.x, gridDim.x * 256);
}
__global__ __launch_bounds__(256) void k_ell(Params p) {
    ell_stage(p, blockIdx.x * 256 + threadIdx.x, gridDim.x * 256);
}
__global__ __launch_bounds__(256) void k_spmm(const int* cnt, const Entry* ent,
                                              const bf16* XC, const bf16* C0C,
                                              float alpha, float beta,
                                              bf16* Zr, bf16* Zi, bf16* ZC) {
    __shared__ __align__(16) char smem[6144];
    spmm_stage(cnt, ent, XC, C0C, alpha, beta, Zr, Zi, ZC, smem, blockIdx.x);
}
__global__ __launch_bounds__(256) void k_wapply(const bf16* Z0r, const bf16* Z0i,
                                                const bf16* Z1r, const bf16* Z1i,
                                                const bf16* Z2r, const bf16* Z2i,
                                                const bf16* Wt, const float* bias,
                                                bf16* Or, bf16* Oi, bf16* OC) {
    __shared__ __align__(16) char smem[12288];
    wapply_stage(Z0r, Z0i, Z1r, Z1i, Z2r, Z2i, Wt, bias, Or, Oi, OC, smem, blockIdx.x);
}
__global__ __launch_bounds__(256) void k_head(const bf16* Yrb, const bf16* Yib,
                                              const bf16* Wcb, const float* bc,
                                              float* out) {
    __shared__ __align__(16) char smem[29440];
    head_stage(Yrb, Yib, Wcb, bc, out, smem, blockIdx.x);
}

// ---------------------------------------------------------------------------
// Launcher: cooperative mega kernel; on launch failure, fall back to the
// proven multi-kernel sequence (identical math).
// ---------------------------------------------------------------------------
extern "C" void kernel_launch(void* const* d_in, const int* in_sizes, int n_in,
                              void* d_out, int out_size, void* d_ws, size_t ws_size,
                              hipStream_t stream) {
    Params p;
    p.real = (const float*)d_in[0];
    p.imag = (const float*)d_in[1];
    p.edges = (const int*)d_in[2];
    p.q    = (const float*)d_in[3];
    p.ew   = (const float*)d_in[4];
    p.W1   = (const float*)d_in[5];
    p.b1   = (const float*)d_in[6];
    p.W2   = (const float*)d_in[7];
    p.b2   = (const float*)d_in[8];
    p.Wc   = (const float*)d_in[9];
    p.bc   = (const float*)d_in[10];
    p.out  = (float*)d_out;

    char* w = (char*)d_ws;
    p.hkey   = (int*)w;   w += (size_t)HSIZE * 4;
    p.hval   = (float*)w; w += (size_t)HSIZE * 4;
    p.cnt    = (int*)w;   w += N_NODES * 4;
    p.rowsum = (float*)w; w += N_NODES * 4;
    p.colsum = (float*)w; w += N_NODES * 4;
    p.ent    = (Entry*)w; w += (size_t)N_NODES * CAP * 16;
    p.Xr16 = (bf16*)w; w += NF * 2;
    p.Xi16 = (bf16*)w; w += NF * 2;
    p.XC   = (bf16*)w; w += NF * 4;
    p.Z1r  = (bf16*)w; w += NF * 2;
    p.Z1i  = (bf16*)w; w += NF * 2;
    p.Z1C  = (bf16*)w; w += NF * 4;
    p.Z2r  = (bf16*)w; w += NF * 2;
    p.Z2i  = (bf16*)w; w += NF * 2;
    p.Y1rb = (bf16*)w; w += NF * 2;
    p.Y1ib = (bf16*)w; w += NF * 2;
    p.Y1C  = (bf16*)w; w += NF * 4;
    p.Y2rb = (bf16*)w; w += NF * 2;
    p.Y2ib = (bf16*)w; w += NF * 2;
    p.W1t  = (bf16*)w; w += 256 * 768 * 2;
    p.W2t  = (bf16*)w; w += 256 * 768 * 2;
    p.Wcb  = (bf16*)w; w += 48 * 512 * 2;

    void* args[] = { &p };
    hipError_t err = hipLaunchCooperativeKernel((void*)mega, dim3(GRID), dim3(256),
                                                args, 0, stream);
    if (err != hipSuccess) {
        (void)hipGetLastError();   // clear error state
        dim3 b(256);
        k_init<<<GRID, b, 0, stream>>>(p);
        k_hash<<<GRID, b, 0, stream>>>(p);
        k_ell<<<GRID, b, 0, stream>>>(p);
        // Layer 1
        k_spmm<<<GRID, b, 0, stream>>>(p.cnt, p.ent, p.XC, nullptr,
                                       1.f, 0.f, p.Z1r, p.Z1i, p.Z1C);
        k_spmm<<<GRID, b, 0, stream>>>(p.cnt, p.ent, p.Z1C, p.XC,
                                       2.f, -1.f, p.Z2r, p.Z2i, nullptr);
        k_wapply<<<256, b, 0, stream>>>(p.Xr16, p.Xi16, p.Z1r, p.Z1i, p.Z2r, p.Z2i,
                                        p.W1t, p.b1, p.Y1rb, p.Y1ib, p.Y1C);
        // Layer 2
        k_spmm<<<GRID, b, 0, stream>>>(p.cnt, p.ent, p.Y1C, nullptr,
                                       1.f, 0.f, p.Z1r, p.Z1i, p.Z1C);
        k_spmm<<<GRID, b, 0, stream>>>(p.cnt, p.ent, p.Z1C, p.Y1C,
                                       2.f, -1.f, p.Z2r, p.Z2i, nullptr);
        k_wapply<<<256, b, 0, stream>>>(p.Y1rb, p.Y1ib, p.Z1r, p.Z1i, p.Z2r, p.Z2i,
                                        p.W2t, p.b2, p.Y2rb, p.Y2ib, nullptr);
        // Head
        k_head<<<64, b, 0, stream>>>(p.Y2rb, p.Y2ib, p.Wcb, p.bc, p.out);
    }
}

// Round 16
// 721.045 us; speedup vs baseline: 1.2248x; 1.2248x over previous
//
#include <hip/hip_runtime.h>
#include <hip/hip_cooperative_groups.h>
#include <cmath>

namespace cg = cooperative_groups;

#define N_NODES 4096
#define FDIM    256
#define CDIM    40
#define NEDGE   131072
#define CAP     256                  // ELL row capacity (row nnz ~Poisson(64))
#define HBITS   20
#define HSIZE   (1 << HBITS)         // 1M hash slots, load <= 0.125
#define TWO_PI_F 6.28318530717958647692f
#define NWT     (256 * 768)

typedef __bf16 bf16;
typedef __bf16 bf16x2 __attribute__((ext_vector_type(2)));
typedef __bf16 bf16x4 __attribute__((ext_vector_type(4)));
typedef __bf16 bf16x8 __attribute__((ext_vector_type(8)));
typedef float  f32x4  __attribute__((ext_vector_type(4)));

static constexpr size_t NF = (size_t)N_NODES * FDIM;      // 1,048,576
static constexpr int ZWORDS = 2 * HSIZE + 3 * N_NODES;    // hkey+hval+cnt+rowsum+colsum

struct __align__(16) Entry { float lr, li; int col, pad; };

struct Params {
    const int* edges; const float* ew; const float* q;
    const float* real; const float* imag;
    const float* W1; const float* b1; const float* W2; const float* b2;
    const float* Wc; const float* bc;
    int* hkey; float* hval; int* cnt; float* rowsum; float* colsum;
    Entry* ent;
    bf16 *Xr16, *Xi16, *XC;
    bf16 *Z1r, *Z1i, *Z1C, *Z2r, *Z2i;
    bf16 *Y1rb, *Y1ib, *Y1C, *Y2rb, *Y2ib;
    bf16 *W1t, *W2t, *Wcb;
    float* out;
};

// async global->LDS, 16B per lane, dest = ldsBase + lane*16
__device__ __forceinline__ void gld_lds16(const bf16* g, bf16* s) {
    __builtin_amdgcn_global_load_lds(
        (const __attribute__((address_space(1))) void*)g,
        (__attribute__((address_space(3))) void*)s,
        16, 0, 0);
}

__device__ __forceinline__ unsigned cell_hash(unsigned cell) {
    return (cell * 2654435761u) >> (32 - HBITS);
}

// ---------------------------------------------------------------------------
// Stage bodies (shared between mega kernel and fallback wrappers).
// All are grid-stride in (bid, nblocks) so any grid size is correct.
// ---------------------------------------------------------------------------
__device__ void init_stage(const Params& p, int gtid, int stride) {
    int* zw = (int*)p.hkey;   // hkey,hval,cnt,rowsum,colsum contiguous
    for (int w0 = gtid; w0 < ZWORDS; w0 += stride) zw[w0] = 0;

    for (int idx = gtid; idx < (int)NF; idx += stride) {
        float vr = p.real[idx], vi = p.imag[idx];
        p.Xr16[idx] = (bf16)vr; p.Xi16[idx] = (bf16)vi;
        bf16x2 pp; pp[0] = (bf16)vr; pp[1] = (bf16)vi;
        ((bf16x2*)p.XC)[idx] = pp;
    }
    for (int idx = gtid; idx < 2 * NWT + 48 * 512; idx += stride) {
        if (idx < 2 * NWT) {
            const float* W = (idx < NWT) ? p.W1 : p.W2;
            bf16* Wt = (idx < NWT) ? p.W1t : p.W2t;
            int id = (idx < NWT) ? idx : idx - NWT;
            int nout = id / 768, kk = id - nout * 768;
            int o = kk >> 8, k = kk & 255;
            Wt[id] = (bf16)W[((size_t)o * 256 + k) * 256 + nout];
        } else {
            int id = idx - 2 * NWT;
            int row = id >> 9, k = id & 511;
            p.Wcb[id] = (row < CDIM) ? (bf16)p.Wc[row * 512 + k] : (bf16)0.f;
        }
    }
}

__device__ void hash_stage(const Params& p, int gtid, int stride) {
    for (int e = gtid; e < NEDGE; e += stride) {
        int r = p.edges[e], c = p.edges[NEDGE + e];
        float wv = p.ew[e];
        atomicAdd(p.rowsum + r, wv);
        atomicAdd(p.colsum + c, wv);
        unsigned cell = (unsigned)r * N_NODES + c;
        unsigned h = cell_hash(cell);
        for (;;) {
            int old = atomicCAS(p.hkey + h, 0, (int)(cell + 1));
            if (old == 0 || old == (int)(cell + 1)) { atomicAdd(p.hval + h, wv); break; }
            h = (h + 1) & (HSIZE - 1);
        }
    }
}

__device__ void ell_stage(const Params& p, int gtid, int stride) {
    for (int h = gtid; h < HSIZE; h += stride) {
        int k = p.hkey[h];
        if (k == 0) continue;
        unsigned cell = (unsigned)(k - 1);
        int i = cell >> 12, j = cell & 4095;
        float a = p.hval[h];
        float b = 0.f;
        bool mirror = false;
        if (i == j) { b = a; mirror = true; }
        else {
            unsigned mcell = (unsigned)j * N_NODES + i;
            unsigned hh = cell_hash(mcell);
            for (;;) {
                int kk = p.hkey[hh];
                if (kk == (int)(mcell + 1)) { b = p.hval[hh]; mirror = true; break; }
                if (kk == 0) break;
                hh = (hh + 1) & (HSIZE - 1);
            }
        }
        float di = 0.5f * (p.rowsum[i] + p.colsum[i]); if (di == 0.f) di = 1.f;
        float dj = 0.5f * (p.rowsum[j] + p.colsum[j]); if (dj == 0.f) dj = 1.f;
        float an = 0.5f * (a + b) / sqrtf(di * dj);
        float s, c;
        sincosf(TWO_PI_F * p.q[0] * (a - b), &s, &c);
        int pos = atomicAdd(p.cnt + i, 1);
        if (pos < CAP) {
            Entry en; en.lr = -an * c; en.li = an * s; en.col = j; en.pad = 0;
            p.ent[(size_t)i * CAP + pos] = en;
        }
        if (!mirror) {
            int pos2 = atomicAdd(p.cnt + j, 1);
            if (pos2 < CAP) {
                Entry en; en.lr = -an * c; en.li = -an * s; en.col = i; en.pad = 0;
                p.ent[(size_t)j * CAP + pos2] = en;
            }
        }
    }
}

// spmm stage (R8/R13-proven math): one row per block-iteration, row-stride.
__device__ void spmm_stage(const int* __restrict__ cnt, const Entry* __restrict__ ent,
                           const bf16* __restrict__ XC, const bf16* __restrict__ C0C,
                           float alpha, float beta,
                           bf16* __restrict__ Zr, bf16* __restrict__ Zi,
                           bf16* __restrict__ ZC, char* smem, int bid, int nblocks)
{
    f32x4* redR = (f32x4*)smem;          // [3][64]
    f32x4* redI = redR + 192;            // [3][64]
    const int wave = threadIdx.x >> 6, lane = threadIdx.x & 63;

    for (int row = bid; row < N_NODES; row += nblocks) {
        int n1 = cnt[row]; if (n1 > CAP) n1 = CAP;
        const Entry* erow = ent + (size_t)row * CAP;

        float ar[4] = {}, ai[4] = {};
        int e = wave;
        for (; e + 12 < n1; e += 16) {
            Entry e0 = erow[e];
            Entry e1 = erow[e + 4];
            Entry e2 = erow[e + 8];
            Entry e3 = erow[e + 12];
            bf16x8 x0 = *(const bf16x8*)&XC[(size_t)(e0.col & 4095) * 512 + lane * 8];
            bf16x8 x1 = *(const bf16x8*)&XC[(size_t)(e1.col & 4095) * 512 + lane * 8];
            bf16x8 x2 = *(const bf16x8*)&XC[(size_t)(e2.col & 4095) * 512 + lane * 8];
            bf16x8 x3 = *(const bf16x8*)&XC[(size_t)(e3.col & 4095) * 512 + lane * 8];
            #pragma unroll
            for (int c = 0; c < 4; ++c) {
                float xr, xi;
                xr = (float)x0[2 * c]; xi = (float)x0[2 * c + 1];
                ar[c] += e0.lr * xr - e0.li * xi;  ai[c] += e0.lr * xi + e0.li * xr;
                xr = (float)x1[2 * c]; xi = (float)x1[2 * c + 1];
                ar[c] += e1.lr * xr - e1.li * xi;  ai[c] += e1.lr * xi + e1.li * xr;
                xr = (float)x2[2 * c]; xi = (float)x2[2 * c + 1];
                ar[c] += e2.lr * xr - e2.li * xi;  ai[c] += e2.lr * xi + e2.li * xr;
                xr = (float)x3[2 * c]; xi = (float)x3[2 * c + 1];
                ar[c] += e3.lr * xr - e3.li * xi;  ai[c] += e3.lr * xi + e3.li * xr;
            }
        }
        for (; e < n1; e += 4) {
            Entry e0 = erow[e];
            bf16x8 x0 = *(const bf16x8*)&XC[(size_t)(e0.col & 4095) * 512 + lane * 8];
            #pragma unroll
            for (int c = 0; c < 4; ++c) {
                float xr0 = (float)x0[2 * c], xi0 = (float)x0[2 * c + 1];
                ar[c] += e0.lr * xr0 - e0.li * xi0;
                ai[c] += e0.lr * xi0 + e0.li * xr0;
            }
        }

        if (wave != 0) {
            f32x4 r, i;
            #pragma unroll
            for (int c = 0; c < 4; ++c) { r[c] = ar[c]; i[c] = ai[c]; }
            redR[(wave - 1) * 64 + lane] = r;
            redI[(wave - 1) * 64 + lane] = i;
        }
        __syncthreads();
        if (wave == 0) {
            #pragma unroll
            for (int w = 0; w < 3; ++w) {
                f32x4 r = redR[w * 64 + lane], i = redI[w * 64 + lane];
                #pragma unroll
                for (int c = 0; c < 4; ++c) { ar[c] += r[c]; ai[c] += i[c]; }
            }
            float vr[4], vi[4];
            if (beta != 0.f) {
                bf16x8 c0 = *(const bf16x8*)&C0C[(size_t)row * 512 + lane * 8];
                #pragma unroll
                for (int c = 0; c < 4; ++c) {
                    vr[c] = alpha * ar[c] + beta * (float)c0[2 * c];
                    vi[c] = alpha * ai[c] + beta * (float)c0[2 * c + 1];
                }
            } else {
                #pragma unroll
                for (int c = 0; c < 4; ++c) { vr[c] = alpha * ar[c]; vi[c] = alpha * ai[c]; }
            }
            size_t base = (size_t)row * FDIM + lane * 4;
            bf16x4 pr, pi;
            #pragma unroll
            for (int c = 0; c < 4; ++c) { pr[c] = (bf16)vr[c]; pi[c] = (bf16)vi[c]; }
            *(bf16x4*)&Zr[base] = pr;
            *(bf16x4*)&Zi[base] = pi;
            if (ZC) {
                bf16x8 o;
                #pragma unroll
                for (int c = 0; c < 4; ++c) { o[2 * c] = pr[c]; o[2 * c + 1] = pi[c]; }
                *(bf16x8*)&ZC[(size_t)row * 512 + lane * 8] = o;
            }
        }
        __syncthreads();   // protect LDS reuse for next row
    }
}

// wapply stage (R3/R7/R9-proven math): tile-stride over 256 64x64 tiles.
__device__ void wapply_stage(const bf16* __restrict__ Z0r, const bf16* __restrict__ Z0i,
                             const bf16* __restrict__ Z1r, const bf16* __restrict__ Z1i,
                             const bf16* __restrict__ Z2r, const bf16* __restrict__ Z2i,
                             const bf16* __restrict__ Wt, const float* __restrict__ bias,
                             bf16* __restrict__ Or, bf16* __restrict__ Oi,
                             bf16* __restrict__ OC, char* smem, int bid, int nblocks)
{
    bf16* sZr = (bf16*)smem;
    bf16* sZi = (bf16*)(smem + 4096);
    bf16* sW  = (bf16*)(smem + 8192);

    const int tid  = threadIdx.x;
    const int wave = tid >> 6;
    const int lane = tid & 63;
    const int wm = wave & 1, wn = wave >> 1;
    const int fr = lane & 15;
    const int fk = (lane >> 4) * 8;
    const int srow = lane >> 2;
    const int skc  = (lane & 3) * 8;

    for (int tile = bid; tile < 256; tile += nblocks) {
        const int rowBase = (tile >> 2) * 64;
        const int colBase = (tile & 3) * 64;

        f32x4 accSr[2][2] = {}, accSi[2][2] = {};

        for (int kb = 0; kb < 3 * FDIM; kb += 32) {
            int order = kb >> 8;
            int kloc  = kb & 255;
            if (wave == 0 || wave == 1) {
                const bf16* z;
                if (wave == 0) z = (order == 0) ? Z0r : (order == 1) ? Z1r : Z2r;
                else           z = (order == 0) ? Z0i : (order == 1) ? Z1i : Z2i;
                bf16* s = (wave == 0) ? sZr : sZi;
                const bf16* g = z + (size_t)(rowBase + srow) * FDIM + kloc + skc;
                #pragma unroll
                for (int t = 0; t < 4; ++t)
                    gld_lds16(g + (size_t)t * 16 * FDIM, s + t * 512);
            } else if (wave == 2) {
                const bf16* g = Wt + (size_t)(colBase + srow) * 768 + kb + skc;
                #pragma unroll
                for (int t = 0; t < 4; ++t)
                    gld_lds16(g + (size_t)t * 16 * 768, sW + t * 512);
            }
            __syncthreads();

            bf16x8 zr[2], zi[2], wv[2];
            #pragma unroll
            for (int m = 0; m < 2; ++m) {
                int r = wm * 32 + m * 16 + fr;
                zr[m] = *(const bf16x8*)&sZr[r * 32 + fk];
                zi[m] = *(const bf16x8*)&sZi[r * 32 + fk];
            }
            #pragma unroll
            for (int n = 0; n < 2; ++n) {
                int c = wn * 32 + n * 16 + fr;
                wv[n] = *(const bf16x8*)&sW[c * 32 + fk];
            }
            #pragma unroll
            for (int m = 0; m < 2; ++m)
                #pragma unroll
                for (int n = 0; n < 2; ++n) {
                    accSr[m][n] = __builtin_amdgcn_mfma_f32_16x16x32_bf16(zr[m], wv[n], accSr[m][n], 0, 0, 0);
                    accSi[m][n] = __builtin_amdgcn_mfma_f32_16x16x32_bf16(zi[m], wv[n], accSi[m][n], 0, 0, 0);
                }
            __syncthreads();
        }

        #pragma unroll
        for (int m = 0; m < 2; ++m)
            #pragma unroll
            for (int n = 0; n < 2; ++n) {
                int row0 = rowBase + wm * 32 + m * 16 + (lane >> 4) * 4;
                int col  = colBase + wn * 32 + n * 16 + (lane & 15);
                float bv = bias[col];
                #pragma unroll
                for (int r = 0; r < 4; ++r) {
                    float vr = bv - accSi[m][n][r];
                    float vi = bv + accSr[m][n][r];
                    size_t idx = (size_t)(row0 + r) * FDIM + col;
                    Or[idx] = (bf16)vr; Oi[idx] = (bf16)vi;
                    if (OC) {
                        bf16x2 pp; pp[0] = (bf16)vr; pp[1] = (bf16)vi;
                        ((bf16x2*)OC)[idx] = pp;
                    }
                }
            }
    }
}

// head stage (R11-proven math): tile-stride over 64 row-tiles.
// LDS: sS aliases sY (sY dead after the kb loop's trailing barrier).
__device__ void head_stage(const bf16* __restrict__ Yrb, const bf16* __restrict__ Yib,
                           const bf16* __restrict__ Wcb, const float* __restrict__ bc,
                           float* __restrict__ out, char* smem, int bid, int nblocks)
{
    bf16*  sY = (bf16*)smem;                       // [64][72] = 9216 B
    bf16*  sW = (bf16*)(smem + 9216);              // [48][72] = 6912 B
    float* sS = (float*)smem;                      // [64][52] = 13312 B (aliases sY)

    const int tid  = threadIdx.x;
    const int wave = tid >> 6;
    const int lane = tid & 63;

    for (int t0 = bid; t0 < 64; t0 += nblocks) {
        const int r0 = t0 * 64;
        f32x4 acc[3] = {};

        for (int kb = 0; kb < 512; kb += 64) {
            const bf16* src = (kb < 256) ? Yrb : Yib;
            const int koff = kb & 255;
            #pragma unroll
            for (int e = 0; e < 2; ++e) {
                int idx = tid + e * 256;
                int rr = idx >> 3, kk = (idx & 7) * 8;
                *(bf16x8*)&sY[rr * 72 + kk] =
                    *(const bf16x8*)&src[(size_t)(r0 + rr) * FDIM + koff + kk];
            }
            #pragma unroll
            for (int e = 0; e < 2; ++e) {
                int idx = tid + e * 256;
                if (idx < 384) {
                    int rr = idx >> 3, kk = (idx & 7) * 8;
                    *(bf16x8*)&sW[rr * 72 + kk] =
                        *(const bf16x8*)&Wcb[(size_t)rr * 512 + kb + kk];
                }
            }
            __syncthreads();
            #pragma unroll
            for (int ks = 0; ks < 2; ++ks) {
                bf16x8 a = *(const bf16x8*)&sY[(wave * 16 + (lane & 15)) * 72 + ks * 32 + (lane >> 4) * 8];
                #pragma unroll
                for (int n = 0; n < 3; ++n) {
                    bf16x8 b = *(const bf16x8*)&sW[(n * 16 + (lane & 15)) * 72 + ks * 32 + (lane >> 4) * 8];
                    acc[n] = __builtin_amdgcn_mfma_f32_16x16x32_bf16(a, b, acc[n], 0, 0, 0);
                }
            }
            __syncthreads();   // after this, sY is dead -> sS may overwrite
        }

        #pragma unroll
        for (int n = 0; n < 3; ++n) {
            int col = n * 16 + (lane & 15);
            int rloc = wave * 16 + (lane >> 4) * 4;
            #pragma unroll
            for (int r = 0; r < 4; ++r)
                sS[(rloc + r) * 52 + col] = acc[n][r];
        }
        __syncthreads();

        if (tid < 64) {
            float mx = -INFINITY;
            #pragma unroll 8
            for (int c = 0; c < CDIM; ++c) {
                float lv = sS[tid * 52 + c] + bc[c];
                sS[tid * 52 + c] = lv;
                mx = fmaxf(mx, lv);
            }
            float se = 0.f;
            #pragma unroll 8
            for (int c = 0; c < CDIM; ++c) se += expf(sS[tid * 52 + c] - mx);
            float lse = mx + logf(se);
            #pragma unroll 8
            for (int c = 0; c < CDIM; ++c)
                out[(size_t)(r0 + tid) * CDIM + c] = sS[tid * 52 + c] - lse;
        }
        __syncthreads();   // sS (alias of sY) must be fully read before next tile
    }
}

// ---------------------------------------------------------------------------
// Mega cooperative kernel. __launch_bounds__(256,8) caps VGPR at 64 so
// 8 blocks/CU are resident (LDS 16.4KB x 8 = 131KB < 160KB). Grid is sized
// by the host occupancy query.
// ---------------------------------------------------------------------------
__global__ __launch_bounds__(256, 8) void mega(Params p) {
    cg::grid_group grid = cg::this_grid();
    __shared__ __align__(16) char smem[16384];

    const int bid  = blockIdx.x;
    const int tid  = threadIdx.x;
    const int nb   = gridDim.x;
    const int gtid = bid * 256 + tid;
    const int stride = nb * 256;

    init_stage(p, gtid, stride);
    grid.sync();
    hash_stage(p, gtid, stride);
    grid.sync();
    ell_stage(p, gtid, stride);
    grid.sync();

    // Layer 1
    spmm_stage(p.cnt, p.ent, p.XC, nullptr, 1.f, 0.f, p.Z1r, p.Z1i, p.Z1C, smem, bid, nb);
    grid.sync();
    spmm_stage(p.cnt, p.ent, p.Z1C, p.XC, 2.f, -1.f, p.Z2r, p.Z2i, nullptr, smem, bid, nb);
    grid.sync();
    wapply_stage(p.Xr16, p.Xi16, p.Z1r, p.Z1i, p.Z2r, p.Z2i,
                 p.W1t, p.b1, p.Y1rb, p.Y1ib, p.Y1C, smem, bid, nb);
    grid.sync();

    // Layer 2
    spmm_stage(p.cnt, p.ent, p.Y1C, nullptr, 1.f, 0.f, p.Z1r, p.Z1i, p.Z1C, smem, bid, nb);
    grid.sync();
    spmm_stage(p.cnt, p.ent, p.Z1C, p.Y1C, 2.f, -1.f, p.Z2r, p.Z2i, nullptr, smem, bid, nb);
    grid.sync();
    wapply_stage(p.Y1rb, p.Y1ib, p.Z1r, p.Z1i, p.Z2r, p.Z2i,
                 p.W2t, p.b2, p.Y2rb, p.Y2ib, nullptr, smem, bid, nb);
    grid.sync();

    // Head
    head_stage(p.Y2rb, p.Y2ib, p.Wcb, p.bc, p.out, smem, bid, nb);
}

// ---------------------------------------------------------------------------
// Fallback wrappers (multi-kernel path, same device bodies) — R13-equivalent.
// ---------------------------------------------------------------------------
__global__ __launch_bounds__(256) void k_init(Params p) {
    init_stage(p, blockIdx.x * 256 + threadIdx.x, gridDim.x * 256);
}
__global__ __launch_bounds__(256) void k_hash(Params p) {
    hash_stage(p, blockIdx.x * 256 + threadIdx.x, gridDim.x * 256);
}
__global__ __launch_bounds__(256) void k_ell(Params p) {
    ell_stage(p, blockIdx.x * 256 + threadIdx.x, gridDim.x * 256);
}
__global__ __launch_bounds__(256) void k_spmm(const int* cnt, const Entry* ent,
                                              const bf16* XC, const bf16* C0C,
                                              float alpha, float beta,
                                              bf16* Zr, bf16* Zi, bf16* ZC) {
    __shared__ __align__(16) char smem[6144];
    spmm_stage(cnt, ent, XC, C0C, alpha, beta, Zr, Zi, ZC, smem, blockIdx.x, gridDim.x);
}
__global__ __launch_bounds__(256) void k_wapply(const bf16* Z0r, const bf16* Z0i,
                                                const bf16* Z1r, const bf16* Z1i,
                                                const bf16* Z2r, const bf16* Z2i,
                                                const bf16* Wt, const float* bias,
                                                bf16* Or, bf16* Oi, bf16* OC) {
    __shared__ __align__(16) char smem[12288];
    wapply_stage(Z0r, Z0i, Z1r, Z1i, Z2r, Z2i, Wt, bias, Or, Oi, OC, smem,
                 blockIdx.x, gridDim.x);
}
__global__ __launch_bounds__(256) void k_head(const bf16* Yrb, const bf16* Yib,
                                              const bf16* Wcb, const float* bc,
                                              float* out) {
    __shared__ __align__(16) char smem[16384];
    head_stage(Yrb, Yib, Wcb, bc, out, smem, blockIdx.x, gridDim.x);
}

// ---------------------------------------------------------------------------
// Launcher: occupancy-sized cooperative mega kernel; multi-kernel fallback.
// ---------------------------------------------------------------------------
extern "C" void kernel_launch(void* const* d_in, const int* in_sizes, int n_in,
                              void* d_out, int out_size, void* d_ws, size_t ws_size,
                              hipStream_t stream) {
    Params p;
    p.real = (const float*)d_in[0];
    p.imag = (const float*)d_in[1];
    p.edges = (const int*)d_in[2];
    p.q    = (const float*)d_in[3];
    p.ew   = (const float*)d_in[4];
    p.W1   = (const float*)d_in[5];
    p.b1   = (const float*)d_in[6];
    p.W2   = (const float*)d_in[7];
    p.b2   = (const float*)d_in[8];
    p.Wc   = (const float*)d_in[9];
    p.bc   = (const float*)d_in[10];
    p.out  = (float*)d_out;

    char* w = (char*)d_ws;
    p.hkey   = (int*)w;   w += (size_t)HSIZE * 4;
    p.hval   = (float*)w; w += (size_t)HSIZE * 4;
    p.cnt    = (int*)w;   w += N_NODES * 4;
    p.rowsum = (float*)w; w += N_NODES * 4;
    p.colsum = (float*)w; w += N_NODES * 4;
    p.ent    = (Entry*)w; w += (size_t)N_NODES * CAP * 16;
    p.Xr16 = (bf16*)w; w += NF * 2;
    p.Xi16 = (bf16*)w; w += NF * 2;
    p.XC   = (bf16*)w; w += NF * 4;
    p.Z1r  = (bf16*)w; w += NF * 2;
    p.Z1i  = (bf16*)w; w += NF * 2;
    p.Z1C  = (bf16*)w; w += NF * 4;
    p.Z2r  = (bf16*)w; w += NF * 2;
    p.Z2i  = (bf16*)w; w += NF * 2;
    p.Y1rb = (bf16*)w; w += NF * 2;
    p.Y1ib = (bf16*)w; w += NF * 2;
    p.Y1C  = (bf16*)w; w += NF * 4;
    p.Y2rb = (bf16*)w; w += NF * 2;
    p.Y2ib = (bf16*)w; w += NF * 2;
    p.W1t  = (bf16*)w; w += 256 * 768 * 2;
    p.W2t  = (bf16*)w; w += 256 * 768 * 2;
    p.Wcb  = (bf16*)w; w += 48 * 512 * 2;

    // Size the cooperative grid to max co-residency (host-side query,
    // capture-safe: no stream ops).
    int bpc = 0;
    hipError_t qerr = hipOccupancyMaxActiveBlocksPerMultiprocessor(
        &bpc, (const void*)mega, 256, 0);
    int grid = (qerr == hipSuccess && bpc > 0) ? bpc * 256 : 0;
    if (grid > 4096) grid = 4096;

    bool launched = false;
    if (grid >= 256) {
        void* args[] = { &p };
        hipError_t err = hipLaunchCooperativeKernel((void*)mega, dim3(grid),
                                                    dim3(256), args, 0, stream);
        launched = (err == hipSuccess);
        if (!launched) (void)hipGetLastError();   // clear error state
    }

    if (!launched) {
        dim3 b(256);
        k_init<<<512, b, 0, stream>>>(p);
        k_hash<<<512, b, 0, stream>>>(p);
        k_ell<<<512, b, 0, stream>>>(p);
        // Layer 1
        k_spmm<<<4096, b, 0, stream>>>(p.cnt, p.ent, p.XC, nullptr,
                                       1.f, 0.f, p.Z1r, p.Z1i, p.Z1C);
        k_spmm<<<4096, b, 0, stream>>>(p.cnt, p.ent, p.Z1C, p.XC,
                                       2.f, -1.f, p.Z2r, p.Z2i, nullptr);
        k_wapply<<<256, b, 0, stream>>>(p.Xr16, p.Xi16, p.Z1r, p.Z1i, p.Z2r, p.Z2i,
                                        p.W1t, p.b1, p.Y1rb, p.Y1ib, p.Y1C);
        // Layer 2
        k_spmm<<<4096, b, 0, stream>>>(p.cnt, p.ent, p.Y1C, nullptr,
                                       1.f, 0.f, p.Z1r, p.Z1i, p.Z1C);
        k_spmm<<<4096, b, 0, stream>>>(p.cnt, p.ent, p.Z1C, p.Y1C,
                                       2.f, -1.f, p.Z2r, p.Z2i, nullptr);
        k_wapply<<<256, b, 0, stream>>>(p.Y1rb, p.Y1ib, p.Z1r, p.Z1i, p.Z2r, p.Z2i,
                                        p.W2t, p.b2, p.Y2rb, p.Y2ib, nullptr);
        // Head
        k_head<<<64, b, 0, stream>>>(p.Y2rb, p.Y2ib, p.Wcb, p.bc, p.out);
    }
}

// Round 17
// 281.968 us; speedup vs baseline: 3.1321x; 2.5572x over previous
//
#include <hip/hip_runtime.h>
#include <cmath>

#define N_NODES 4096
#define FDIM    256
#define CDIM    40
#define NEDGE   131072
#define CAP     256                  // ELL row capacity (row nnz ~Poisson(64))
#define HBITS   20
#define HSIZE   (1 << HBITS)         // 1M hash slots, load <= 0.125
#define TWO_PI_F 6.28318530717958647692f
#define NWT     (256 * 768)

typedef __bf16 bf16;
typedef __bf16 bf16x2 __attribute__((ext_vector_type(2)));
typedef __bf16 bf16x4 __attribute__((ext_vector_type(4)));
typedef __bf16 bf16x8 __attribute__((ext_vector_type(8)));
typedef float  f32x4  __attribute__((ext_vector_type(4)));

static constexpr size_t NF = (size_t)N_NODES * FDIM;      // 1,048,576
static constexpr int ZWORDS = 2 * HSIZE + 3 * N_NODES;    // hkey+hval+cnt+rowsum+colsum

struct __align__(16) Entry { float lr, li; int col, pad; };

struct Params {
    const int* edges; const float* ew; const float* q;
    const float* real; const float* imag;
    const float* W1; const float* b1; const float* W2; const float* b2;
    const float* Wc; const float* bc;
    int* hkey; float* hval; int* cnt; float* rowsum; float* colsum;
    Entry* ent;
    bf16 *Xr16, *Xi16, *XC;
    bf16 *Z1r, *Z1i, *Z1C, *Z2r, *Z2i;
    bf16 *Y1rb, *Y1ib, *Y1C, *Y2rb, *Y2ib;
    bf16 *W1t, *W2t, *Wcb;
    float* out;
};

// async global->LDS, 16B per lane, dest = ldsBase + lane*16
__device__ __forceinline__ void gld_lds16(const bf16* g, bf16* s) {
    __builtin_amdgcn_global_load_lds(
        (const __attribute__((address_space(1))) void*)g,
        (__attribute__((address_space(3))) void*)s,
        16, 0, 0);
}

__device__ __forceinline__ unsigned cell_hash(unsigned cell) {
    return (cell * 2654435761u) >> (32 - HBITS);
}

// ---------------------------------------------------------------------------
// Stage bodies (R8/R11/R13-proven math; grid-stride in (bid, nblocks)).
// ---------------------------------------------------------------------------
__device__ void init_stage(const Params& p, int gtid, int stride) {
    int* zw = (int*)p.hkey;   // hkey,hval,cnt,rowsum,colsum contiguous
    for (int w0 = gtid; w0 < ZWORDS; w0 += stride) zw[w0] = 0;

    for (int idx = gtid; idx < (int)NF; idx += stride) {
        float vr = p.real[idx], vi = p.imag[idx];
        p.Xr16[idx] = (bf16)vr; p.Xi16[idx] = (bf16)vi;
        bf16x2 pp; pp[0] = (bf16)vr; pp[1] = (bf16)vi;
        ((bf16x2*)p.XC)[idx] = pp;
    }
    for (int idx = gtid; idx < 2 * NWT + 48 * 512; idx += stride) {
        if (idx < 2 * NWT) {
            const float* W = (idx < NWT) ? p.W1 : p.W2;
            bf16* Wt = (idx < NWT) ? p.W1t : p.W2t;
            int id = (idx < NWT) ? idx : idx - NWT;
            int nout = id / 768, kk = id - nout * 768;
            int o = kk >> 8, k = kk & 255;
            Wt[id] = (bf16)W[((size_t)o * 256 + k) * 256 + nout];
        } else {
            int id = idx - 2 * NWT;
            int row = id >> 9, k = id & 511;
            p.Wcb[id] = (row < CDIM) ? (bf16)p.Wc[row * 512 + k] : (bf16)0.f;
        }
    }
}

__device__ void hash_stage(const Params& p, int gtid, int stride) {
    for (int e = gtid; e < NEDGE; e += stride) {
        int r = p.edges[e], c = p.edges[NEDGE + e];
        float wv = p.ew[e];
        atomicAdd(p.rowsum + r, wv);
        atomicAdd(p.colsum + c, wv);
        unsigned cell = (unsigned)r * N_NODES + c;
        unsigned h = cell_hash(cell);
        for (;;) {
            int old = atomicCAS(p.hkey + h, 0, (int)(cell + 1));
            if (old == 0 || old == (int)(cell + 1)) { atomicAdd(p.hval + h, wv); break; }
            h = (h + 1) & (HSIZE - 1);
        }
    }
}

__device__ void ell_stage(const Params& p, int gtid, int stride) {
    for (int h = gtid; h < HSIZE; h += stride) {
        int k = p.hkey[h];
        if (k == 0) continue;
        unsigned cell = (unsigned)(k - 1);
        int i = cell >> 12, j = cell & 4095;
        float a = p.hval[h];
        float b = 0.f;
        bool mirror = false;
        if (i == j) { b = a; mirror = true; }
        else {
            unsigned mcell = (unsigned)j * N_NODES + i;
            unsigned hh = cell_hash(mcell);
            for (;;) {
                int kk = p.hkey[hh];
                if (kk == (int)(mcell + 1)) { b = p.hval[hh]; mirror = true; break; }
                if (kk == 0) break;
                hh = (hh + 1) & (HSIZE - 1);
            }
        }
        float di = 0.5f * (p.rowsum[i] + p.colsum[i]); if (di == 0.f) di = 1.f;
        float dj = 0.5f * (p.rowsum[j] + p.colsum[j]); if (dj == 0.f) dj = 1.f;
        float an = 0.5f * (a + b) / sqrtf(di * dj);
        float s, c;
        sincosf(TWO_PI_F * p.q[0] * (a - b), &s, &c);
        int pos = atomicAdd(p.cnt + i, 1);
        if (pos < CAP) {
            Entry en; en.lr = -an * c; en.li = an * s; en.col = j; en.pad = 0;
            p.ent[(size_t)i * CAP + pos] = en;
        }
        if (!mirror) {
            int pos2 = atomicAdd(p.cnt + j, 1);
            if (pos2 < CAP) {
                Entry en; en.lr = -an * c; en.li = -an * s; en.col = i; en.pad = 0;
                p.ent[(size_t)j * CAP + pos2] = en;
            }
        }
    }
}

// spmm: one row per block-iteration, row-stride (grid 4096 -> exactly 1/block).
__device__ void spmm_stage(const int* __restrict__ cnt, const Entry* __restrict__ ent,
                           const bf16* __restrict__ XC, const bf16* __restrict__ C0C,
                           float alpha, float beta,
                           bf16* __restrict__ Zr, bf16* __restrict__ Zi,
                           bf16* __restrict__ ZC, char* smem, int bid, int nblocks)
{
    f32x4* redR = (f32x4*)smem;          // [3][64]
    f32x4* redI = redR + 192;            // [3][64]
    const int wave = threadIdx.x >> 6, lane = threadIdx.x & 63;

    for (int row = bid; row < N_NODES; row += nblocks) {
        int n1 = cnt[row]; if (n1 > CAP) n1 = CAP;
        const Entry* erow = ent + (size_t)row * CAP;

        float ar[4] = {}, ai[4] = {};
        int e = wave;
        for (; e + 12 < n1; e += 16) {
            Entry e0 = erow[e];
            Entry e1 = erow[e + 4];
            Entry e2 = erow[e + 8];
            Entry e3 = erow[e + 12];
            bf16x8 x0 = *(const bf16x8*)&XC[(size_t)(e0.col & 4095) * 512 + lane * 8];
            bf16x8 x1 = *(const bf16x8*)&XC[(size_t)(e1.col & 4095) * 512 + lane * 8];
            bf16x8 x2 = *(const bf16x8*)&XC[(size_t)(e2.col & 4095) * 512 + lane * 8];
            bf16x8 x3 = *(const bf16x8*)&XC[(size_t)(e3.col & 4095) * 512 + lane * 8];
            #pragma unroll
            for (int c = 0; c < 4; ++c) {
                float xr, xi;
                xr = (float)x0[2 * c]; xi = (float)x0[2 * c + 1];
                ar[c] += e0.lr * xr - e0.li * xi;  ai[c] += e0.lr * xi + e0.li * xr;
                xr = (float)x1[2 * c]; xi = (float)x1[2 * c + 1];
                ar[c] += e1.lr * xr - e1.li * xi;  ai[c] += e1.lr * xi + e1.li * xr;
                xr = (float)x2[2 * c]; xi = (float)x2[2 * c + 1];
                ar[c] += e2.lr * xr - e2.li * xi;  ai[c] += e2.lr * xi + e2.li * xr;
                xr = (float)x3[2 * c]; xi = (float)x3[2 * c + 1];
                ar[c] += e3.lr * xr - e3.li * xi;  ai[c] += e3.lr * xi + e3.li * xr;
            }
        }
        for (; e < n1; e += 4) {
            Entry e0 = erow[e];
            bf16x8 x0 = *(const bf16x8*)&XC[(size_t)(e0.col & 4095) * 512 + lane * 8];
            #pragma unroll
            for (int c = 0; c < 4; ++c) {
                float xr0 = (float)x0[2 * c], xi0 = (float)x0[2 * c + 1];
                ar[c] += e0.lr * xr0 - e0.li * xi0;
                ai[c] += e0.lr * xi0 + e0.li * xr0;
            }
        }

        if (wave != 0) {
            f32x4 r, i;
            #pragma unroll
            for (int c = 0; c < 4; ++c) { r[c] = ar[c]; i[c] = ai[c]; }
            redR[(wave - 1) * 64 + lane] = r;
            redI[(wave - 1) * 64 + lane] = i;
        }
        __syncthreads();
        if (wave == 0) {
            #pragma unroll
            for (int w = 0; w < 3; ++w) {
                f32x4 r = redR[w * 64 + lane], i = redI[w * 64 + lane];
                #pragma unroll
                for (int c = 0; c < 4; ++c) { ar[c] += r[c]; ai[c] += i[c]; }
            }
            float vr[4], vi[4];
            if (beta != 0.f) {
                bf16x8 c0 = *(const bf16x8*)&C0C[(size_t)row * 512 + lane * 8];
                #pragma unroll
                for (int c = 0; c < 4; ++c) {
                    vr[c] = alpha * ar[c] + beta * (float)c0[2 * c];
                    vi[c] = alpha * ai[c] + beta * (float)c0[2 * c + 1];
                }
            } else {
                #pragma unroll
                for (int c = 0; c < 4; ++c) { vr[c] = alpha * ar[c]; vi[c] = alpha * ai[c]; }
            }
            size_t base = (size_t)row * FDIM + lane * 4;
            bf16x4 pr, pi;
            #pragma unroll
            for (int c = 0; c < 4; ++c) { pr[c] = (bf16)vr[c]; pi[c] = (bf16)vi[c]; }
            *(bf16x4*)&Zr[base] = pr;
            *(bf16x4*)&Zi[base] = pi;
            if (ZC) {
                bf16x8 o;
                #pragma unroll
                for (int c = 0; c < 4; ++c) { o[2 * c] = pr[c]; o[2 * c + 1] = pi[c]; }
                *(bf16x8*)&ZC[(size_t)row * 512 + lane * 8] = o;
            }
        }
        __syncthreads();   // protect LDS reuse (no-op when 1 row/block)
    }
}

// wapply: tile-stride over 256 64x64 tiles (grid 256 -> exactly 1/block).
__device__ void wapply_stage(const bf16* __restrict__ Z0r, const bf16* __restrict__ Z0i,
                             const bf16* __restrict__ Z1r, const bf16* __restrict__ Z1i,
                             const bf16* __restrict__ Z2r, const bf16* __restrict__ Z2i,
                             const bf16* __restrict__ Wt, const float* __restrict__ bias,
                             bf16* __restrict__ Or, bf16* __restrict__ Oi,
                             bf16* __restrict__ OC, char* smem, int bid, int nblocks)
{
    bf16* sZr = (bf16*)smem;
    bf16* sZi = (bf16*)(smem + 4096);
    bf16* sW  = (bf16*)(smem + 8192);

    const int tid  = threadIdx.x;
    const int wave = tid >> 6;
    const int lane = tid & 63;
    const int wm = wave & 1, wn = wave >> 1;
    const int fr = lane & 15;
    const int fk = (lane >> 4) * 8;
    const int srow = lane >> 2;
    const int skc  = (lane & 3) * 8;

    for (int tile = bid; tile < 256; tile += nblocks) {
        const int rowBase = (tile >> 2) * 64;
        const int colBase = (tile & 3) * 64;

        f32x4 accSr[2][2] = {}, accSi[2][2] = {};

        for (int kb = 0; kb < 3 * FDIM; kb += 32) {
            int order = kb >> 8;
            int kloc  = kb & 255;
            if (wave == 0 || wave == 1) {
                const bf16* z;
                if (wave == 0) z = (order == 0) ? Z0r : (order == 1) ? Z1r : Z2r;
                else           z = (order == 0) ? Z0i : (order == 1) ? Z1i : Z2i;
                bf16* s = (wave == 0) ? sZr : sZi;
                const bf16* g = z + (size_t)(rowBase + srow) * FDIM + kloc + skc;
                #pragma unroll
                for (int t = 0; t < 4; ++t)
                    gld_lds16(g + (size_t)t * 16 * FDIM, s + t * 512);
            } else if (wave == 2) {
                const bf16* g = Wt + (size_t)(colBase + srow) * 768 + kb + skc;
                #pragma unroll
                for (int t = 0; t < 4; ++t)
                    gld_lds16(g + (size_t)t * 16 * 768, sW + t * 512);
            }
            __syncthreads();

            bf16x8 zr[2], zi[2], wv[2];
            #pragma unroll
            for (int m = 0; m < 2; ++m) {
                int r = wm * 32 + m * 16 + fr;
                zr[m] = *(const bf16x8*)&sZr[r * 32 + fk];
                zi[m] = *(const bf16x8*)&sZi[r * 32 + fk];
            }
            #pragma unroll
            for (int n = 0; n < 2; ++n) {
                int c = wn * 32 + n * 16 + fr;
                wv[n] = *(const bf16x8*)&sW[c * 32 + fk];
            }
            #pragma unroll
            for (int m = 0; m < 2; ++m)
                #pragma unroll
                for (int n = 0; n < 2; ++n) {
                    accSr[m][n] = __builtin_amdgcn_mfma_f32_16x16x32_bf16(zr[m], wv[n], accSr[m][n], 0, 0, 0);
                    accSi[m][n] = __builtin_amdgcn_mfma_f32_16x16x32_bf16(zi[m], wv[n], accSi[m][n], 0, 0, 0);
                }
            __syncthreads();
        }

        #pragma unroll
        for (int m = 0; m < 2; ++m)
            #pragma unroll
            for (int n = 0; n < 2; ++n) {
                int row0 = rowBase + wm * 32 + m * 16 + (lane >> 4) * 4;
                int col  = colBase + wn * 32 + n * 16 + (lane & 15);
                float bv = bias[col];
                #pragma unroll
                for (int r = 0; r < 4; ++r) {
                    float vr = bv - accSi[m][n][r];
                    float vi = bv + accSr[m][n][r];
                    size_t idx = (size_t)(row0 + r) * FDIM + col;
                    Or[idx] = (bf16)vr; Oi[idx] = (bf16)vi;
                    if (OC) {
                        bf16x2 pp; pp[0] = (bf16)vr; pp[1] = (bf16)vi;
                        ((bf16x2*)OC)[idx] = pp;
                    }
                }
            }
    }
}

// head: tile-stride over 64 row-tiles (grid 64 -> exactly 1/block).
// sS aliases sY (sY dead after the kb loop's trailing barrier).
__device__ void head_stage(const bf16* __restrict__ Yrb, const bf16* __restrict__ Yib,
                           const bf16* __restrict__ Wcb, const float* __restrict__ bc,
                           float* __restrict__ out, char* smem, int bid, int nblocks)
{
    bf16*  sY = (bf16*)smem;                       // [64][72] = 9216 B
    bf16*  sW = (bf16*)(smem + 9216);              // [48][72] = 6912 B
    float* sS = (float*)smem;                      // [64][52] (aliases sY)

    const int tid  = threadIdx.x;
    const int wave = tid >> 6;
    const int lane = tid & 63;

    for (int t0 = bid; t0 < 64; t0 += nblocks) {
        const int r0 = t0 * 64;
        f32x4 acc[3] = {};

        for (int kb = 0; kb < 512; kb += 64) {
            const bf16* src = (kb < 256) ? Yrb : Yib;
            const int koff = kb & 255;
            #pragma unroll
            for (int e = 0; e < 2; ++e) {
                int idx = tid + e * 256;
                int rr = idx >> 3, kk = (idx & 7) * 8;
                *(bf16x8*)&sY[rr * 72 + kk] =
                    *(const bf16x8*)&src[(size_t)(r0 + rr) * FDIM + koff + kk];
            }
            #pragma unroll
            for (int e = 0; e < 2; ++e) {
                int idx = tid + e * 256;
                if (idx < 384) {
                    int rr = idx >> 3, kk = (idx & 7) * 8;
                    *(bf16x8*)&sW[rr * 72 + kk] =
                        *(const bf16x8*)&Wcb[(size_t)rr * 512 + kb + kk];
                }
            }
            __syncthreads();
            #pragma unroll
            for (int ks = 0; ks < 2; ++ks) {
                bf16x8 a = *(const bf16x8*)&sY[(wave * 16 + (lane & 15)) * 72 + ks * 32 + (lane >> 4) * 8];
                #pragma unroll
                for (int n = 0; n < 3; ++n) {
                    bf16x8 b = *(const bf16x8*)&sW[(n * 16 + (lane & 15)) * 72 + ks * 32 + (lane >> 4) * 8];
                    acc[n] = __builtin_amdgcn_mfma_f32_16x16x32_bf16(a, b, acc[n], 0, 0, 0);
                }
            }
            __syncthreads();   // after this, sY is dead -> sS may overwrite
        }

        #pragma unroll
        for (int n = 0; n < 3; ++n) {
            int col = n * 16 + (lane & 15);
            int rloc = wave * 16 + (lane >> 4) * 4;
            #pragma unroll
            for (int r = 0; r < 4; ++r)
                sS[(rloc + r) * 52 + col] = acc[n][r];
        }
        __syncthreads();

        if (tid < 64) {
            float mx = -INFINITY;
            #pragma unroll 8
            for (int c = 0; c < CDIM; ++c) {
                float lv = sS[tid * 52 + c] + bc[c];
                sS[tid * 52 + c] = lv;
                mx = fmaxf(mx, lv);
            }
            float se = 0.f;
            #pragma unroll 8
            for (int c = 0; c < CDIM; ++c) se += expf(sS[tid * 52 + c] - mx);
            float lse = mx + logf(se);
            #pragma unroll 8
            for (int c = 0; c < CDIM; ++c)
                out[(size_t)(r0 + tid) * CDIM + c] = sS[tid * 52 + c] - lse;
        }
        __syncthreads();
    }
}

// ---------------------------------------------------------------------------
// Kernels (multi-kernel path only — cooperative mega abandoned: R15/R16
// showed grid.sync costs ~80 µs each on MI355X, 9 syncs >> 10 launches).
// ---------------------------------------------------------------------------
__global__ __launch_bounds__(256) void k_init(Params p) {
    init_stage(p, blockIdx.x * 256 + threadIdx.x, gridDim.x * 256);
}
__global__ __launch_bounds__(256) void k_hash(Params p) {
    hash_stage(p, blockIdx.x * 256 + threadIdx.x, gridDim.x * 256);
}
__global__ __launch_bounds__(256) void k_ell(Params p) {
    ell_stage(p, blockIdx.x * 256 + threadIdx.x, gridDim.x * 256);
}
__global__ __launch_bounds__(256) void k_spmm(const int* cnt, const Entry* ent,
                                              const bf16* XC, const bf16* C0C,
                                              float alpha, float beta,
                                              bf16* Zr, bf16* Zi, bf16* ZC) {
    __shared__ __align__(16) char smem[6144];
    spmm_stage(cnt, ent, XC, C0C, alpha, beta, Zr, Zi, ZC, smem, blockIdx.x, gridDim.x);
}
__global__ __launch_bounds__(256) void k_wapply(const bf16* Z0r, const bf16* Z0i,
                                                const bf16* Z1r, const bf16* Z1i,
                                                const bf16* Z2r, const bf16* Z2i,
                                                const bf16* Wt, const float* bias,
                                                bf16* Or, bf16* Oi, bf16* OC) {
    __shared__ __align__(16) char smem[12288];
    wapply_stage(Z0r, Z0i, Z1r, Z1i, Z2r, Z2i, Wt, bias, Or, Oi, OC, smem,
                 blockIdx.x, gridDim.x);
}
__global__ __launch_bounds__(256) void k_head(const bf16* Yrb, const bf16* Yib,
                                              const bf16* Wcb, const float* bc,
                                              float* out) {
    __shared__ __align__(16) char smem[16384];
    head_stage(Yrb, Yib, Wcb, bc, out, smem, blockIdx.x, gridDim.x);
}

// ---------------------------------------------------------------------------
// Launcher: 10-node multi-kernel sequence.
// ---------------------------------------------------------------------------
extern "C" void kernel_launch(void* const* d_in, const int* in_sizes, int n_in,
                              void* d_out, int out_size, void* d_ws, size_t ws_size,
                              hipStream_t stream) {
    Params p;
    p.real = (const float*)d_in[0];
    p.imag = (const float*)d_in[1];
    p.edges = (const int*)d_in[2];
    p.q    = (const float*)d_in[3];
    p.ew   = (const float*)d_in[4];
    p.W1   = (const float*)d_in[5];
    p.b1   = (const float*)d_in[6];
    p.W2   = (const float*)d_in[7];
    p.b2   = (const float*)d_in[8];
    p.Wc   = (const float*)d_in[9];
    p.bc   = (const float*)d_in[10];
    p.out  = (float*)d_out;

    char* w = (char*)d_ws;
    p.hkey   = (int*)w;   w += (size_t)HSIZE * 4;
    p.hval   = (float*)w; w += (size_t)HSIZE * 4;
    p.cnt    = (int*)w;   w += N_NODES * 4;
    p.rowsum = (float*)w; w += N_NODES * 4;
    p.colsum = (float*)w; w += N_NODES * 4;
    p.ent    = (Entry*)w; w += (size_t)N_NODES * CAP * 16;
    p.Xr16 = (bf16*)w; w += NF * 2;
    p.Xi16 = (bf16*)w; w += NF * 2;
    p.XC   = (bf16*)w; w += NF * 4;
    p.Z1r  = (bf16*)w; w += NF * 2;
    p.Z1i  = (bf16*)w; w += NF * 2;
    p.Z1C  = (bf16*)w; w += NF * 4;
    p.Z2r  = (bf16*)w; w += NF * 2;
    p.Z2i  = (bf16*)w; w += NF * 2;
    p.Y1rb = (bf16*)w; w += NF * 2;
    p.Y1ib = (bf16*)w; w += NF * 2;
    p.Y1C  = (bf16*)w; w += NF * 4;
    p.Y2rb = (bf16*)w; w += NF * 2;
    p.Y2ib = (bf16*)w; w += NF * 2;
    p.W1t  = (bf16*)w; w += 256 * 768 * 2;
    p.W2t  = (bf16*)w; w += 256 * 768 * 2;
    p.Wcb  = (bf16*)w; w += 48 * 512 * 2;

    dim3 b(256);
    k_init<<<512, b, 0, stream>>>(p);
    k_hash<<<512, b, 0, stream>>>(p);
    k_ell<<<512, b, 0, stream>>>(p);
    // Layer 1
    k_spmm<<<4096, b, 0, stream>>>(p.cnt, p.ent, p.XC, nullptr,
                                   1.f, 0.f, p.Z1r, p.Z1i, p.Z1C);
    k_spmm<<<4096, b, 0, stream>>>(p.cnt, p.ent, p.Z1C, p.XC,
                                   2.f, -1.f, p.Z2r, p.Z2i, nullptr);
    k_wapply<<<256, b, 0, stream>>>(p.Xr16, p.Xi16, p.Z1r, p.Z1i, p.Z2r, p.Z2i,
                                    p.W1t, p.b1, p.Y1rb, p.Y1ib, p.Y1C);
    // Layer 2
    k_spmm<<<4096, b, 0, stream>>>(p.cnt, p.ent, p.Y1C, nullptr,
                                   1.f, 0.f, p.Z1r, p.Z1i, p.Z1C);
    k_spmm<<<4096, b, 0, stream>>>(p.cnt, p.ent, p.Z1C, p.Y1C,
                                   2.f, -1.f, p.Z2r, p.Z2i, nullptr);
    k_wapply<<<256, b, 0, stream>>>(p.Y1rb, p.Y1ib, p.Z1r, p.Z1i, p.Z2r, p.Z2i,
                                    p.W2t, p.b2, p.Y2rb, p.Y2ib, nullptr);
    // Head
    k_head<<<64, b, 0, stream>>>(p.Y2rb, p.Y2ib, p.Wcb, p.bc, p.out);
}